// Round 10
// baseline (54.906 us; speedup 1.0000x reference)
//
#include <hip/hip_runtime.h>
#include <math.h>

#define NB 16
#define NG 32
#define NM 320
#define NN 960      // 3 * NM
#define NA 3
#define NCH 85
#define NC 80
#define NK 20

// ---------------- DPP wave-reduce helpers ----------------
template<int CTRL>
__device__ __forceinline__ unsigned long long dpp_u64_self(unsigned long long x) {
    int lo = (int)(unsigned)(x & 0xFFFFFFFFull);
    int hi = (int)(unsigned)(x >> 32);
    int lo2 = __builtin_amdgcn_update_dpp(lo, lo, CTRL, 0xF, 0xF, false);
    int hi2 = __builtin_amdgcn_update_dpp(hi, hi, CTRL, 0xF, 0xF, false);
    return ((unsigned long long)(unsigned)hi2 << 32) | (unsigned)lo2;
}

__device__ __forceinline__ unsigned long long dpp_max_u64(unsigned long long x) {
    unsigned long long o;
    o = dpp_u64_self<0x111>(x); x = (o > x) ? o : x;   // row_shr:1
    o = dpp_u64_self<0x112>(x); x = (o > x) ? o : x;   // row_shr:2
    o = dpp_u64_self<0x114>(x); x = (o > x) ? o : x;   // row_shr:4
    o = dpp_u64_self<0x118>(x); x = (o > x) ? o : x;   // row_shr:8
    o = dpp_u64_self<0x142>(x); x = (o > x) ? o : x;   // row_bcast:15
    o = dpp_u64_self<0x143>(x); x = (o > x) ? o : x;   // row_bcast:31
    return x;
}

__device__ __forceinline__ unsigned long long dpp_min_u64(unsigned long long x) {
    unsigned long long o;
    o = dpp_u64_self<0x111>(x); x = (o < x) ? o : x;
    o = dpp_u64_self<0x112>(x); x = (o < x) ? o : x;
    o = dpp_u64_self<0x114>(x); x = (o < x) ? o : x;
    o = dpp_u64_self<0x118>(x); x = (o < x) ? o : x;
    o = dpp_u64_self<0x142>(x); x = (o < x) ? o : x;
    o = dpp_u64_self<0x143>(x); x = (o < x) ? o : x;
    return x;
}

template<int CTRL>
__device__ __forceinline__ double dpp_f64_zero(double x) {
    long long b = __double_as_longlong(x);
    int lo = (int)(unsigned)((unsigned long long)b & 0xFFFFFFFFull);
    int hi = (int)(unsigned)((unsigned long long)b >> 32);
    int lo2 = __builtin_amdgcn_update_dpp(0, lo, CTRL, 0xF, 0xF, true);
    int hi2 = __builtin_amdgcn_update_dpp(0, hi, CTRL, 0xF, 0xF, true);
    unsigned long long r = ((unsigned long long)(unsigned)hi2 << 32) | (unsigned)lo2;
    return __longlong_as_double((long long)r);
}

__device__ __forceinline__ double dpp_sum_f64(double x) {
    x += dpp_f64_zero<0x111>(x);
    x += dpp_f64_zero<0x112>(x);
    x += dpp_f64_zero<0x114>(x);
    x += dpp_f64_zero<0x118>(x);
    x += dpp_f64_zero<0x142>(x);
    x += dpp_f64_zero<0x143>(x);
    return x;   // lane 63 holds the total
}

// ---------------- K1: prep — 64 candidates/block, LDS-transposed coalesced zT ----------------
// grid = NB*15 blocks of 256 (4 waves); wave w handles candidates n0 + w*16 .. +15.
__global__ __launch_bounds__(256) void k_prep(
                       const float* __restrict__ p0, const float* __restrict__ p1, const float* __restrict__ p2,
                       const int* __restrict__ a0, const int* __restrict__ gj0, const int* __restrict__ gi0,
                       const int* __restrict__ a1, const int* __restrict__ gj1, const int* __restrict__ gi1,
                       const int* __restrict__ a2, const int* __restrict__ gj2, const int* __restrict__ gi2,
                       float4* __restrict__ pm1, float* __restrict__ zT,
                       double* __restrict__ Ssum)
{
    __shared__ float zt[NC][65];   // +1 pad: write banks (cc+ci)%32, read conflict-free

    int blk = (int)blockIdx.x;
    int b = blk / 15;
    int n0 = (blk % 15) * 64;
    int t = (int)threadIdx.x;
    int lane = t & 63;
    int w = t >> 6;

    for (int k = 0; k < 16; ++k) {
        int ci = w * 16 + k;           // local candidate 0..63
        int n = n0 + ci;
        int wid = b * NN + n;
        int lvl = (n < NM) ? 0 : ((n < 2 * NM) ? 1 : 2);
        int m = n - lvl * NM;

        const int* pa = (lvl == 0) ? a0 : ((lvl == 1) ? a1 : a2);
        const int* pj = (lvl == 0) ? gj0 : ((lvl == 1) ? gj1 : gj2);
        const int* pi = (lvl == 0) ? gi0 : ((lvl == 1) ? gi1 : gi2);
        const float* pr = (lvl == 0) ? p0 : ((lvl == 1) ? p1 : p2);
        int h = (lvl == 0) ? 80 : ((lvl == 1) ? 40 : 20);
        float s = (lvl == 0) ? 8.0f : ((lvl == 1) ? 16.0f : 32.0f);

        int aa = pa[b * NM + m];
        int jj = pj[b * NM + m];
        int ii = pi[b * NM + m];
        int off = (((b * NA + aa) * h + jj) * h + ii) * NCH;
        const float* c = pr + off;

        float po = c[4];
        double S = 0.0;
        for (int cc = lane; cc < NC; cc += 64) {
            float pc = c[5 + cc];
            float y = sqrtf(pc * po);
            float z = logf(y / (1.0f - y));
            float sp = fmaxf(z, 0.0f) + log1pf(expf(-fabsf(z)));
            S += (double)sp;
            zt[cc][ci] = z;
        }
        S = dpp_sum_f64(S);   // valid in lane 63

        if (lane == 63) {
            float cx = c[0] * s, cy = c[1] * s, ww = c[2] * s, hh = c[3] * s;
            float x1 = cx - ww * 0.5f, y1 = cy - hh * 0.5f;
            float x2 = cx + ww * 0.5f, y2 = cy + hh * 0.5f;
            pm1[wid] = make_float4(x1, y1, x2, y2);
            Ssum[wid] = S;
        }
    }
    __syncthreads();

    // coalesced zT output: 80*64 floats, 256 threads x 20 iters
    #pragma unroll
    for (int p = 0; p < 20; ++p) {
        int idx = p * 256 + t;
        int c = idx >> 6;          // class row
        int nl = idx & 63;         // local n
        zT[(size_t)(b * NC + c) * NN + n0 + nl] = zt[c][nl];
    }
}

// ---------------- K2: one wave per (b, g) row ----------------
__global__ __launch_bounds__(64) void k_row(
        const float* __restrict__ tgt,
        const float4* __restrict__ pm1, const float* __restrict__ zT,
        const double* __restrict__ Ssum,
        unsigned long long* __restrict__ mb, float* __restrict__ ocost)
{
    int bg = blockIdx.x;            // bg = b*NG + g
    int b = bg / NG;
    int t = (int)threadIdx.x;

    const float* tg = tgt + bg * 6;
    int cls = (int)tg[1];
    float gcx = tg[2] * 640.0f, gcy = tg[3] * 640.0f;
    float gw = tg[4] * 640.0f, gh = tg[5] * 640.0f;
    float gx1 = gcx - gw * 0.5f, gy1 = gcy - gh * 0.5f;
    float gx2 = gcx + gw * 0.5f, gy2 = gcy + gh * 0.5f;
    float ga = (gx2 - gx1) * (gy2 - gy1);

    const float* zrow = zT + (size_t)(b * NC + cls) * NN;

    float cl[15], io[15];
    #pragma unroll
    for (int j = 0; j < 15; ++j) {
        int n = j * 64 + t;
        int idx = b * NN + n;
        float4 m1 = pm1[idx];
        float area = (m1.z - m1.x) * (m1.w - m1.y);
        float z = zrow[n];                            // coalesced
        float clsl = (float)(Ssum[idx] - (double)z);

        float lx = fmaxf(gx1, m1.x), ly = fmaxf(gy1, m1.y);
        float rx = fminf(gx2, m1.z), ry = fminf(gy2, m1.w);
        float wx = fmaxf(rx - lx, 0.0f), wy = fmaxf(ry - ly, 0.0f);
        float inter = wx * wy;
        float iou = inter / (ga + area - inter);
        float il = -logf(iou + 1e-5f);
        float cst = clsl + 3.0f * il;

        cl[j] = cst;
        io[j] = iou;
        ocost[bg * NN + n] = cst;
    }

    // ---- dk: sum of top-20 iou (iou >= 0, bits monotonic; tie -> lowest n)
    double ssum = 0.0;
    for (int k = 0; k < NK; ++k) {
        float bv = io[0]; int bj = 0;
        #pragma unroll
        for (int j = 1; j < 15; ++j) {
            if (io[j] > bv) { bv = io[j]; bj = j; }
        }
        unsigned long long key =
            ((unsigned long long)__float_as_uint(bv) << 32) | (unsigned)(~(unsigned)(bj * 64 + t));
        key = dpp_max_u64(key);
        unsigned lo = (unsigned)__builtin_amdgcn_readlane((int)(unsigned)(key & 0xFFFFFFFFull), 63);
        unsigned hi = (unsigned)__builtin_amdgcn_readlane((int)(unsigned)(key >> 32), 63);
        float mval = __uint_as_float(hi);
        int mn = (int)(~lo);
        ssum += (double)mval;
        bool win = ((mn & 63) == t);
        int slot = mn >> 6;
        #pragma unroll
        for (int j = 0; j < 15; ++j) io[j] = (win && slot == j) ? -2.0f : io[j];
    }
    int dk = (int)((float)ssum);
    if (dk < 1) dk = 1;
    if (dk > NK) dk = NK;

    // ---- select dk smallest costs (tie -> lowest n)
    unsigned sel = 0;
    for (int k = 0; k < dk; ++k) {
        float bv = cl[0]; int bj = 0;
        #pragma unroll
        for (int j = 1; j < 15; ++j) {
            if (cl[j] < bv) { bv = cl[j]; bj = j; }
        }
        unsigned long long key =
            ((unsigned long long)__float_as_uint(bv) << 32) | (unsigned)(bj * 64 + t);
        key = dpp_min_u64(key);
        unsigned lo = (unsigned)__builtin_amdgcn_readlane((int)(unsigned)(key & 0xFFFFFFFFull), 63);
        int mn = (int)lo;
        bool win = ((mn & 63) == t);
        int slot = mn >> 6;
        if (win) sel |= 1u << slot;
        #pragma unroll
        for (int j = 0; j < 15; ++j) cl[j] = (win && slot == j) ? INFINITY : cl[j];
    }

    // ---- publish this row's selection as a 960-bit mask (15 x u64)
    #pragma unroll
    for (int j = 0; j < 15; ++j) {
        unsigned long long m = __ballot((sel >> j) & 1u);
        if (t == 0) mb[bg * 15 + j] = m;
    }
}

// ---------------- K3: resolve — one wave per (batch, 64-column word) ----------------
__global__ __launch_bounds__(64) void k_resolve(
        const unsigned long long* __restrict__ mb, const float* __restrict__ ocost,
        float* __restrict__ om, float* __restrict__ ofg, float* __restrict__ omg)
{
    int blk = (int)blockIdx.x;     // 240 = 16 batches x 15 words
    int b = blk / 15;
    int j = blk % 15;
    int t = (int)threadIdx.x;
    int n = j * 64 + t;

    unsigned mloc = 0;
    #pragma unroll
    for (int gg = 0; gg < NG; ++gg) {
        unsigned long long wg = mb[(b * NG + gg) * 15 + j];   // wave-uniform address
        mloc |= (unsigned)((wg >> t) & 1ull) << gg;
    }
    int cnt = __popc(mloc);

    int mgt, fg;
    if (cnt > 1) {
        float bv = INFINITY; int bgi = 0;
        #pragma unroll
        for (int gg = 0; gg < NG; ++gg) {
            float c = ocost[(b * NG + gg) * NN + n];
            if (c < bv) { bv = c; bgi = gg; }
        }
        mloc = 1u << bgi;
        mgt = bgi;
        fg = 1;
    } else {
        mgt = (cnt > 0) ? (__ffs(mloc) - 1) : 0;
        fg = (cnt > 0) ? 1 : 0;
    }

    #pragma unroll
    for (int gg = 0; gg < NG; ++gg) {
        om[(b * NG + gg) * NN + n] = ((mloc >> gg) & 1u) ? 1.0f : 0.0f;
    }
    ofg[b * NN + n] = fg ? 1.0f : 0.0f;
    omg[b * NN + n] = (float)mgt;
}

extern "C" void kernel_launch(void* const* d_in, const int* in_sizes, int n_in,
                              void* d_out, int out_size, void* d_ws, size_t ws_size,
                              hipStream_t stream) {
    const float* p0 = (const float*)d_in[0];
    const int* a0 = (const int*)d_in[1];
    const int* gj0 = (const int*)d_in[2];
    const int* gi0 = (const int*)d_in[3];
    const float* p1 = (const float*)d_in[5];
    const int* a1 = (const int*)d_in[6];
    const int* gj1 = (const int*)d_in[7];
    const int* gi1 = (const int*)d_in[8];
    const float* p2 = (const float*)d_in[10];
    const int* a2 = (const int*)d_in[11];
    const int* gj2 = (const int*)d_in[12];
    const int* gi2 = (const int*)d_in[13];
    const float* tgt = (const float*)d_in[15];

    // Output layout (ALL float32, concatenated in return order):
    // matching (NB*NG*NN) | fg (NB*NN) | matched_gt (NB*NN) | cost (NB*NG*NN)
    float* o = (float*)d_out;
    float* om = o;
    float* ofg = o + (size_t)NB * NG * NN;
    float* omg = ofg + (size_t)NB * NN;
    float* ocost = omg + (size_t)NB * NN;

    // Workspace carve (16B-aligned first)
    char* w = (char*)d_ws;
    float4* pm1 = (float4*)w;               w += (size_t)NB * NN * sizeof(float4);
    float* zT = (float*)w;                  w += (size_t)NB * NC * NN * sizeof(float);
    double* Ssum = (double*)w;              w += (size_t)NB * NN * sizeof(double);
    unsigned long long* mb = (unsigned long long*)w;  w += (size_t)NB * NG * 15 * sizeof(unsigned long long);

    (void)in_sizes; (void)n_in; (void)out_size; (void)ws_size;

    k_prep<<<NB * 15, 256, 0, stream>>>(
        p0, p1, p2, a0, gj0, gi0, a1, gj1, gi1, a2, gj2, gi2,
        pm1, zT, Ssum);

    k_row<<<NB * NG, 64, 0, stream>>>(
        tgt, pm1, zT, Ssum, mb, ocost);

    k_resolve<<<NB * 15, 64, 0, stream>>>(
        mb, ocost, om, ofg, omg);
}

// Round 11
// 45.908 us; speedup vs baseline: 1.1960x; 1.1960x over previous
//
#include <hip/hip_runtime.h>
#include <math.h>

#define NB 16
#define NG 32
#define NM 320
#define NN 960      // 3 * NM
#define NA 3
#define NCH 85
#define NC 80
#define NK 20

// ---------------- DPP wave-reduce helpers ----------------
template<int CTRL>
__device__ __forceinline__ unsigned long long dpp_u64_self(unsigned long long x) {
    int lo = (int)(unsigned)(x & 0xFFFFFFFFull);
    int hi = (int)(unsigned)(x >> 32);
    int lo2 = __builtin_amdgcn_update_dpp(lo, lo, CTRL, 0xF, 0xF, false);
    int hi2 = __builtin_amdgcn_update_dpp(hi, hi, CTRL, 0xF, 0xF, false);
    return ((unsigned long long)(unsigned)hi2 << 32) | (unsigned)lo2;
}

__device__ __forceinline__ unsigned long long dpp_max_u64(unsigned long long x) {
    unsigned long long o;
    o = dpp_u64_self<0x111>(x); x = (o > x) ? o : x;   // row_shr:1
    o = dpp_u64_self<0x112>(x); x = (o > x) ? o : x;   // row_shr:2
    o = dpp_u64_self<0x114>(x); x = (o > x) ? o : x;   // row_shr:4
    o = dpp_u64_self<0x118>(x); x = (o > x) ? o : x;   // row_shr:8
    o = dpp_u64_self<0x142>(x); x = (o > x) ? o : x;   // row_bcast:15
    o = dpp_u64_self<0x143>(x); x = (o > x) ? o : x;   // row_bcast:31
    return x;
}

__device__ __forceinline__ unsigned long long dpp_min_u64(unsigned long long x) {
    unsigned long long o;
    o = dpp_u64_self<0x111>(x); x = (o < x) ? o : x;
    o = dpp_u64_self<0x112>(x); x = (o < x) ? o : x;
    o = dpp_u64_self<0x114>(x); x = (o < x) ? o : x;
    o = dpp_u64_self<0x118>(x); x = (o < x) ? o : x;
    o = dpp_u64_self<0x142>(x); x = (o < x) ? o : x;
    o = dpp_u64_self<0x143>(x); x = (o < x) ? o : x;
    return x;
}

template<int CTRL>
__device__ __forceinline__ double dpp_f64_zero(double x) {
    long long b = __double_as_longlong(x);
    int lo = (int)(unsigned)((unsigned long long)b & 0xFFFFFFFFull);
    int hi = (int)(unsigned)((unsigned long long)b >> 32);
    int lo2 = __builtin_amdgcn_update_dpp(0, lo, CTRL, 0xF, 0xF, true);
    int hi2 = __builtin_amdgcn_update_dpp(0, hi, CTRL, 0xF, 0xF, true);
    unsigned long long r = ((unsigned long long)(unsigned)hi2 << 32) | (unsigned)lo2;
    return __longlong_as_double((long long)r);
}

__device__ __forceinline__ double dpp_sum_f64(double x) {
    x += dpp_f64_zero<0x111>(x);
    x += dpp_f64_zero<0x112>(x);
    x += dpp_f64_zero<0x114>(x);
    x += dpp_f64_zero<0x118>(x);
    x += dpp_f64_zero<0x142>(x);
    x += dpp_f64_zero<0x143>(x);
    return x;   // lane 63 holds the total
}

// ---------------- K1: prep — 16 candidates/block (4 waves x 4 serial), LDS-transposed zT ----
// grid = NB*60 blocks of 256. High TLP (~4 blocks/CU) + coalesced zT flush.
__global__ __launch_bounds__(256) void k_prep(
                       const float* __restrict__ p0, const float* __restrict__ p1, const float* __restrict__ p2,
                       const int* __restrict__ a0, const int* __restrict__ gj0, const int* __restrict__ gi0,
                       const int* __restrict__ a1, const int* __restrict__ gj1, const int* __restrict__ gi1,
                       const int* __restrict__ a2, const int* __restrict__ gj2, const int* __restrict__ gi2,
                       float4* __restrict__ pm1, float* __restrict__ zT,
                       double* __restrict__ Ssum)
{
    __shared__ float zt[NC][17];   // 16 candidates + pad

    int blk = (int)blockIdx.x;
    int b = blk / 60;
    int n0 = (blk % 60) * 16;
    int t = (int)threadIdx.x;
    int lane = t & 63;
    int w = t >> 6;

    #pragma unroll
    for (int k = 0; k < 4; ++k) {
        int ci = w * 4 + k;            // local candidate 0..15
        int n = n0 + ci;
        int wid = b * NN + n;
        int lvl = (n < NM) ? 0 : ((n < 2 * NM) ? 1 : 2);
        int m = n - lvl * NM;

        const int* pa = (lvl == 0) ? a0 : ((lvl == 1) ? a1 : a2);
        const int* pj = (lvl == 0) ? gj0 : ((lvl == 1) ? gj1 : gj2);
        const int* pi = (lvl == 0) ? gi0 : ((lvl == 1) ? gi1 : gi2);
        const float* pr = (lvl == 0) ? p0 : ((lvl == 1) ? p1 : p2);
        int h = (lvl == 0) ? 80 : ((lvl == 1) ? 40 : 20);
        float s = (lvl == 0) ? 8.0f : ((lvl == 1) ? 16.0f : 32.0f);

        int aa = pa[b * NM + m];
        int jj = pj[b * NM + m];
        int ii = pi[b * NM + m];
        int off = (((b * NA + aa) * h + jj) * h + ii) * NCH;
        const float* c = pr + off;

        float po = c[4];
        double S = 0.0;
        for (int cc = lane; cc < NC; cc += 64) {
            float pc = c[5 + cc];
            float y = sqrtf(pc * po);
            float z = logf(y / (1.0f - y));
            float sp = fmaxf(z, 0.0f) + log1pf(expf(-fabsf(z)));
            S += (double)sp;
            zt[cc][ci] = z;
        }
        S = dpp_sum_f64(S);   // valid in lane 63

        if (lane == 63) {
            float cx = c[0] * s, cy = c[1] * s, ww = c[2] * s, hh = c[3] * s;
            float x1 = cx - ww * 0.5f, y1 = cy - hh * 0.5f;
            float x2 = cx + ww * 0.5f, y2 = cy + hh * 0.5f;
            pm1[wid] = make_float4(x1, y1, x2, y2);
            Ssum[wid] = S;
        }
    }
    __syncthreads();

    // coalesced zT flush: 80 classes x 16 candidates = 1280 floats, 256 threads x 5
    #pragma unroll
    for (int p = 0; p < 5; ++p) {
        int idx = p * 256 + t;
        int c = idx >> 4;          // class row 0..79
        int nl = idx & 15;         // local candidate
        zT[(size_t)(b * NC + c) * NN + n0 + nl] = zt[c][nl];
    }
}

// ---------------- K2: one wave per (b, g) row ----------------
__global__ __launch_bounds__(64) void k_row(
        const float* __restrict__ tgt,
        const float4* __restrict__ pm1, const float* __restrict__ zT,
        const double* __restrict__ Ssum,
        unsigned long long* __restrict__ mb, float* __restrict__ ocost)
{
    int bg = blockIdx.x;            // bg = b*NG + g
    int b = bg / NG;
    int t = (int)threadIdx.x;

    const float* tg = tgt + bg * 6;
    int cls = (int)tg[1];
    float gcx = tg[2] * 640.0f, gcy = tg[3] * 640.0f;
    float gw = tg[4] * 640.0f, gh = tg[5] * 640.0f;
    float gx1 = gcx - gw * 0.5f, gy1 = gcy - gh * 0.5f;
    float gx2 = gcx + gw * 0.5f, gy2 = gcy + gh * 0.5f;
    float ga = (gx2 - gx1) * (gy2 - gy1);

    const float* zrow = zT + (size_t)(b * NC + cls) * NN;

    float cl[15], io[15];
    #pragma unroll
    for (int j = 0; j < 15; ++j) {
        int n = j * 64 + t;
        int idx = b * NN + n;
        float4 m1 = pm1[idx];
        float area = (m1.z - m1.x) * (m1.w - m1.y);
        float z = zrow[n];                            // coalesced
        float clsl = (float)(Ssum[idx] - (double)z);

        float lx = fmaxf(gx1, m1.x), ly = fmaxf(gy1, m1.y);
        float rx = fminf(gx2, m1.z), ry = fminf(gy2, m1.w);
        float wx = fmaxf(rx - lx, 0.0f), wy = fmaxf(ry - ly, 0.0f);
        float inter = wx * wy;
        float iou = inter / (ga + area - inter);
        float il = -logf(iou + 1e-5f);
        float cst = clsl + 3.0f * il;

        cl[j] = cst;
        io[j] = iou;
        ocost[bg * NN + n] = cst;
    }

    // ---- dk: sum of top-20 iou (iou >= 0, bits monotonic; tie -> lowest n)
    double ssum = 0.0;
    for (int k = 0; k < NK; ++k) {
        float bv = io[0]; int bj = 0;
        #pragma unroll
        for (int j = 1; j < 15; ++j) {
            if (io[j] > bv) { bv = io[j]; bj = j; }
        }
        unsigned long long key =
            ((unsigned long long)__float_as_uint(bv) << 32) | (unsigned)(~(unsigned)(bj * 64 + t));
        key = dpp_max_u64(key);
        unsigned lo = (unsigned)__builtin_amdgcn_readlane((int)(unsigned)(key & 0xFFFFFFFFull), 63);
        unsigned hi = (unsigned)__builtin_amdgcn_readlane((int)(unsigned)(key >> 32), 63);
        float mval = __uint_as_float(hi);
        int mn = (int)(~lo);
        ssum += (double)mval;
        bool win = ((mn & 63) == t);
        int slot = mn >> 6;
        #pragma unroll
        for (int j = 0; j < 15; ++j) io[j] = (win && slot == j) ? -2.0f : io[j];
    }
    int dk = (int)((float)ssum);
    if (dk < 1) dk = 1;
    if (dk > NK) dk = NK;

    // ---- select dk smallest costs (tie -> lowest n)
    unsigned sel = 0;
    for (int k = 0; k < dk; ++k) {
        float bv = cl[0]; int bj = 0;
        #pragma unroll
        for (int j = 1; j < 15; ++j) {
            if (cl[j] < bv) { bv = cl[j]; bj = j; }
        }
        unsigned long long key =
            ((unsigned long long)__float_as_uint(bv) << 32) | (unsigned)(bj * 64 + t);
        key = dpp_min_u64(key);
        unsigned lo = (unsigned)__builtin_amdgcn_readlane((int)(unsigned)(key & 0xFFFFFFFFull), 63);
        int mn = (int)lo;
        bool win = ((mn & 63) == t);
        int slot = mn >> 6;
        if (win) sel |= 1u << slot;
        #pragma unroll
        for (int j = 0; j < 15; ++j) cl[j] = (win && slot == j) ? INFINITY : cl[j];
    }

    // ---- publish this row's selection as a 960-bit mask (15 x u64)
    #pragma unroll
    for (int j = 0; j < 15; ++j) {
        unsigned long long m = __ballot((sel >> j) & 1u);
        if (t == 0) mb[bg * 15 + j] = m;
    }
}

// ---------------- K3: resolve — one wave per (batch, 64-column word) ----------------
__global__ __launch_bounds__(64) void k_resolve(
        const unsigned long long* __restrict__ mb, const float* __restrict__ ocost,
        float* __restrict__ om, float* __restrict__ ofg, float* __restrict__ omg)
{
    int blk = (int)blockIdx.x;     // 240 = 16 batches x 15 words
    int b = blk / 15;
    int j = blk % 15;
    int t = (int)threadIdx.x;
    int n = j * 64 + t;

    unsigned mloc = 0;
    #pragma unroll
    for (int gg = 0; gg < NG; ++gg) {
        unsigned long long wg = mb[(b * NG + gg) * 15 + j];   // wave-uniform address
        mloc |= (unsigned)((wg >> t) & 1ull) << gg;
    }
    int cnt = __popc(mloc);

    int mgt, fg;
    if (cnt > 1) {
        float bv = INFINITY; int bgi = 0;
        #pragma unroll
        for (int gg = 0; gg < NG; ++gg) {
            float c = ocost[(b * NG + gg) * NN + n];
            if (c < bv) { bv = c; bgi = gg; }
        }
        mloc = 1u << bgi;
        mgt = bgi;
        fg = 1;
    } else {
        mgt = (cnt > 0) ? (__ffs(mloc) - 1) : 0;
        fg = (cnt > 0) ? 1 : 0;
    }

    #pragma unroll
    for (int gg = 0; gg < NG; ++gg) {
        om[(b * NG + gg) * NN + n] = ((mloc >> gg) & 1u) ? 1.0f : 0.0f;
    }
    ofg[b * NN + n] = fg ? 1.0f : 0.0f;
    omg[b * NN + n] = (float)mgt;
}

extern "C" void kernel_launch(void* const* d_in, const int* in_sizes, int n_in,
                              void* d_out, int out_size, void* d_ws, size_t ws_size,
                              hipStream_t stream) {
    const float* p0 = (const float*)d_in[0];
    const int* a0 = (const int*)d_in[1];
    const int* gj0 = (const int*)d_in[2];
    const int* gi0 = (const int*)d_in[3];
    const float* p1 = (const float*)d_in[5];
    const int* a1 = (const int*)d_in[6];
    const int* gj1 = (const int*)d_in[7];
    const int* gi1 = (const int*)d_in[8];
    const float* p2 = (const float*)d_in[10];
    const int* a2 = (const int*)d_in[11];
    const int* gj2 = (const int*)d_in[12];
    const int* gi2 = (const int*)d_in[13];
    const float* tgt = (const float*)d_in[15];

    // Output layout (ALL float32, concatenated in return order):
    // matching (NB*NG*NN) | fg (NB*NN) | matched_gt (NB*NN) | cost (NB*NG*NN)
    float* o = (float*)d_out;
    float* om = o;
    float* ofg = o + (size_t)NB * NG * NN;
    float* omg = ofg + (size_t)NB * NN;
    float* ocost = omg + (size_t)NB * NN;

    // Workspace carve (16B-aligned first)
    char* w = (char*)d_ws;
    float4* pm1 = (float4*)w;               w += (size_t)NB * NN * sizeof(float4);
    float* zT = (float*)w;                  w += (size_t)NB * NC * NN * sizeof(float);
    double* Ssum = (double*)w;              w += (size_t)NB * NN * sizeof(double);
    unsigned long long* mb = (unsigned long long*)w;  w += (size_t)NB * NG * 15 * sizeof(unsigned long long);

    (void)in_sizes; (void)n_in; (void)out_size; (void)ws_size;

    k_prep<<<NB * 60, 256, 0, stream>>>(
        p0, p1, p2, a0, gj0, gi0, a1, gj1, gi1, a2, gj2, gi2,
        pm1, zT, Ssum);

    k_row<<<NB * NG, 64, 0, stream>>>(
        tgt, pm1, zT, Ssum, mb, ocost);

    k_resolve<<<NB * 15, 64, 0, stream>>>(
        mb, ocost, om, ofg, omg);
}